// Round 1
// 274.348 us; speedup vs baseline: 1.0357x; 1.0357x over previous
//
#include <hip/hip_runtime.h>
#include <hip/hip_bf16.h>

typedef __attribute__((ext_vector_type(8))) short short8;
typedef __attribute__((ext_vector_type(4))) float float4v;
typedef __attribute__((ext_vector_type(4))) unsigned int uint4v;
typedef __attribute__((ext_vector_type(2))) unsigned int uint2v;

#define SS 8192
#define EE 512
#define HH 64
#define NKB 16

__device__ __forceinline__ unsigned int f2bf1(float f) {
    unsigned int u = __builtin_bit_cast(unsigned int, f);
    return (u + 0x7fffu + ((u >> 16) & 1u)) >> 16;   // RNE, inputs finite
}
__device__ __forceinline__ unsigned int pack2(float lo, float hi) {
    return f2bf1(lo) | (f2bf1(hi) << 16);
}
__device__ __forceinline__ void gl_lds16(const void* g, void* l) {
    __builtin_amdgcn_global_load_lds(
        (const __attribute__((address_space(1))) void*)g,
        (__attribute__((address_space(3))) void*)l, 16, 0, 0);
}

// ---------- prep: W fp32 [512][512] -> bf16 tiled ws [ntile][kb][n][k32] ----------
__global__ void w_prep(const float* __restrict__ W, unsigned short* __restrict__ Wws) {
    int idx = blockIdx.x * 256 + threadIdx.x;        // 65536 threads x 4 elems
    int r  = idx >> 7;                               // row 0..511 (n-tile major)
    int kg = idx & 127;                              // k-group of 4
    int k  = kg * 4;
    float4v v = *(const float4v*)(W + (size_t)r * EE + k);
    int ntile = r >> 7, n = r & 127, kb = k >> 5, kk = k & 31;
    unsigned short* dst = Wws + (((size_t)(ntile * 16 + kb) * 128 + n) * 32 + kk);
    uint2v pk = { pack2(v.x, v.y), pack2(v.z, v.w) };
    *(uint2v*)dst = pk;
}

// ---------- main v3: reg-staged W pipeline, depth-4 prefetch, counted waits ----------
// Key change vs v2: __syncthreads (vmcnt(0) drain) in the K-loop is replaced by
// raw s_barrier + lgkmcnt(0). W slices travel global->regs (issued 4 iterations
// ahead; compiler emits counted vmcnt(6) waits that keep later loads in flight
// across barriers) -> ds_write -> LDS double buffer. One barrier per iteration.
// A_lds XOR-swizzled: elem [h][j] at shorts h*512 + ((j>>3) ^ (h&7))*8 + (j&7)
__global__ __launch_bounds__(256, 2)
void qmha_fused3(const float* __restrict__ x, const float* __restrict__ theta,
                 const unsigned short* __restrict__ Wws, float* __restrict__ out)
{
    __shared__ __attribute__((aligned(16))) unsigned short A_lds[HH * 512];     // 65536 B
    __shared__ __attribute__((aligned(16))) unsigned short W_lds[2][128 * 32];  // 2 x 8192 B

    const int bx    = blockIdx.x;
    const int ntile = (bx >> 3) & 3;                 // 4 ntiles of same chunk on same XCD
    const int p     = ((bx >> 5) << 3) | (bx & 7);
    const int b     = p >> 7;
    const int sc    = p & 127;

    const int t = threadIdx.x, lane = t & 63, wid = t >> 6;

    const unsigned short* Wtile = Wws + (size_t)ntile * 16 * 4096;  // 16 slices of 4096 shorts
    const int woff = wid * 1024 + lane * 8;          // shorts; wave-contiguous 16B/lane
    const unsigned short* wsrc = Wtile + woff;

    // Issue W slices 0..3 into registers before staging (~2k cycles of cover).
    short8 wa[4], wb[4];
    #pragma unroll
    for (int s = 0; s < 4; ++s) {
        wa[s] = *(const short8*)(wsrc + (size_t)s * 4096);
        wb[s] = *(const short8*)(wsrc + (size_t)s * 4096 + 512);
    }

    const float th0 = theta[0], th1 = theta[1], th2 = theta[2], th3 = theta[3];
    const float th4 = theta[4], th5 = theta[5], th6 = theta[6], th7 = theta[7];

    // A staging: x[b, sc*64 .. +64, :] -> cos -> bf16 -> swizzled A_lds
    {
        const float* xb = x + ((size_t)b * SS + (size_t)sc * 64) * EE + lane * 8;
        const int sw = lane & 7;
        #pragma unroll
        for (int it = 0; it < 16; ++it) {
            const int s_loc = wid * 16 + it;
            const float* px = xb + (size_t)s_loc * EE;
            float4v v0 = *(const float4v*)(px);
            float4v v1 = *(const float4v*)(px + 4);
            float c0 = __cosf(v0.x + th0);
            float c1 = __cosf(v0.y + th1);
            float c2 = __cosf(v0.z + th2);
            float c3 = __cosf(v0.w + th3);
            float c4 = __cosf(v1.x + th4);
            float c5 = __cosf(v1.y + th5);
            float c6 = __cosf(v1.z + th6);
            float c7 = __cosf(v1.w + th7);
            uint4v pk = { pack2(c0,c1), pack2(c2,c3), pack2(c4,c5), pack2(c6,c7) };
            *(uint4v*)&A_lds[lane * 512 + ((s_loc ^ sw) * 8)] = pk;
        }
    }

    float4v acc[2][4];
    #pragma unroll
    for (int i = 0; i < 2; ++i)
        #pragma unroll
        for (int j = 0; j < 4; ++j)
            acc[i][j] = (float4v){0.f, 0.f, 0.f, 0.f};

    const int m0  = (wid >> 1) * 32;
    const int n0l = (wid & 1) * 64;
    const int fr  = lane & 15;
    const int q   = lane >> 4;
    const int swA = fr & 7;                          // (m0+fr)&7 == fr&7 since m0%32==0
    const int aBase0 = (m0 + fr) * 512;
    const int aBase1 = aBase0 + 16 * 512;
    const int bOff   = (n0l + fr) * 32 + q * 8;      // unpadded stride-32: conflict-free

    // A writes visible. W reg-loads stay in flight across this barrier.
    asm volatile("s_waitcnt lgkmcnt(0)" ::: "memory");
    __builtin_amdgcn_s_barrier();

    #pragma unroll
    for (int kb = 0; kb < NKB; ++kb) {
        // Stage slice kb regs -> LDS. Compiler auto-inserts counted vmcnt (6) here,
        // leaving slices kb+1..kb+3 in flight (T4: never drain to 0 in main loop).
        unsigned short* Wd = (unsigned short*)W_lds[kb & 1] + woff;
        *(short8*)(Wd)       = wa[kb & 3];
        *(short8*)(Wd + 512) = wb[kb & 3];
        // Issue slice kb+4 (depth-4 prefetch, ~1400 cycles of cover).
        if (kb + 4 < NKB) {
            wa[kb & 3] = *(const short8*)(wsrc + (size_t)(kb + 4) * 4096);
            wb[kb & 3] = *(const short8*)(wsrc + (size_t)(kb + 4) * 4096 + 512);
        }
        // ds_writes committed, then barrier. NO vmcnt drain: prefetch loads cross.
        asm volatile("s_waitcnt lgkmcnt(0)" ::: "memory");
        __builtin_amdgcn_s_barrier();
        asm volatile("" ::: "memory");               // pin reads after the barrier

        const unsigned short* Bbuf = (const unsigned short*)W_lds[kb & 1];
        const int g = ((kb * 4 + q) ^ swA) * 8;

        short8 a0 = *(const short8*)&A_lds[aBase0 + g];
        short8 a1 = *(const short8*)&A_lds[aBase1 + g];
        short8 b0 = *(const short8*)&Bbuf[bOff + 0 * 16 * 32];
        short8 b1 = *(const short8*)&Bbuf[bOff + 1 * 16 * 32];
        short8 b2 = *(const short8*)&Bbuf[bOff + 2 * 16 * 32];
        short8 b3 = *(const short8*)&Bbuf[bOff + 3 * 16 * 32];

        __builtin_amdgcn_s_setprio(1);
        acc[0][0] = __builtin_amdgcn_mfma_f32_16x16x32_bf16(a0, b0, acc[0][0], 0, 0, 0);
        acc[0][1] = __builtin_amdgcn_mfma_f32_16x16x32_bf16(a0, b1, acc[0][1], 0, 0, 0);
        acc[0][2] = __builtin_amdgcn_mfma_f32_16x16x32_bf16(a0, b2, acc[0][2], 0, 0, 0);
        acc[0][3] = __builtin_amdgcn_mfma_f32_16x16x32_bf16(a0, b3, acc[0][3], 0, 0, 0);
        acc[1][0] = __builtin_amdgcn_mfma_f32_16x16x32_bf16(a1, b0, acc[1][0], 0, 0, 0);
        acc[1][1] = __builtin_amdgcn_mfma_f32_16x16x32_bf16(a1, b1, acc[1][1], 0, 0, 0);
        acc[1][2] = __builtin_amdgcn_mfma_f32_16x16x32_bf16(a1, b2, acc[1][2], 0, 0, 0);
        acc[1][3] = __builtin_amdgcn_mfma_f32_16x16x32_bf16(a1, b3, acc[1][3], 0, 0, 0);
        __builtin_amdgcn_s_setprio(0);
        // No trailing barrier needed: buf[(kb+1)&1] was last read at kb-1, and the
        // barrier above already proves every wave consumed those reads.
    }

    // epilogue: C/D layout col=lane&15, row=(lane>>4)*4+reg (round-1-validated)
    const int colbase = ntile * 128 + n0l + fr;
    #pragma unroll
    for (int mt = 0; mt < 2; ++mt) {
        #pragma unroll
        for (int r = 0; r < 4; ++r) {
            const int hrow = m0 + mt * 16 + q * 4 + r;
            float* po = out + ((size_t)b * SS + (size_t)hrow * 128 + sc) * EE + colbase;
            po[0 * 16] = acc[mt][0][r];
            po[1 * 16] = acc[mt][1][r];
            po[2 * 16] = acc[mt][2][r];
            po[3 * 16] = acc[mt][3][r];
        }
    }
}

// ---------- fallback (round-1 kernel, used only if ws too small) ----------
#define AS 520
#define WSF 40
__global__ __launch_bounds__(256, 2)
void qmha_fused_fb(const float* __restrict__ x, const float* __restrict__ theta,
                   const float* __restrict__ W, float* __restrict__ out)
{
    __shared__ __attribute__((aligned(16))) unsigned short A_lds[HH * AS];
    __shared__ __attribute__((aligned(16))) unsigned short W_lds[128 * WSF];
    const int bx = blockIdx.x;
    const int ntile = (bx >> 3) & 3;
    const int p = ((bx >> 5) << 3) | (bx & 7);
    const int b = p >> 7;
    const int sc = p & 127;
    const int t = threadIdx.x, lane = t & 63, wid = t >> 6;
    const int wn = t >> 1, wk = (t & 1) * 16;
    const float* Wbase = W + (size_t)(ntile * 128 + wn) * EE + wk;
    float4v wv0 = *(const float4v*)(Wbase + 0);
    float4v wv1 = *(const float4v*)(Wbase + 4);
    float4v wv2 = *(const float4v*)(Wbase + 8);
    float4v wv3 = *(const float4v*)(Wbase + 12);
    const float th0 = theta[0], th1 = theta[1], th2 = theta[2], th3 = theta[3];
    const float th4 = theta[4], th5 = theta[5], th6 = theta[6], th7 = theta[7];
    {
        const float* xb = x + ((size_t)b * SS + (size_t)sc * 64) * EE + lane * 8;
        #pragma unroll
        for (int it = 0; it < 16; ++it) {
            const int s_loc = wid * 16 + it;
            const float* px = xb + (size_t)s_loc * EE;
            float4v v0 = *(const float4v*)(px);
            float4v v1 = *(const float4v*)(px + 4);
            float c0 = __cosf(v0.x + th0), c1 = __cosf(v0.y + th1);
            float c2 = __cosf(v0.z + th2), c3 = __cosf(v0.w + th3);
            float c4 = __cosf(v1.x + th4), c5 = __cosf(v1.y + th5);
            float c6 = __cosf(v1.z + th6), c7 = __cosf(v1.w + th7);
            uint4v pk = { pack2(c0,c1), pack2(c2,c3), pack2(c4,c5), pack2(c6,c7) };
            *(uint4v*)&A_lds[lane * AS + s_loc * 8] = pk;
        }
    }
    float4v acc[2][4];
    #pragma unroll
    for (int i = 0; i < 2; ++i)
        #pragma unroll
        for (int j = 0; j < 4; ++j)
            acc[i][j] = (float4v){0.f, 0.f, 0.f, 0.f};
    const int m0 = (wid >> 1) * 32, n0l = (wid & 1) * 64;
    const int fr = lane & 15, q = lane >> 4;
    const unsigned short* Arow0 = &A_lds[(m0 + fr) * AS + q * 8];
    const unsigned short* Arow1 = Arow0 + 16 * AS;
    const unsigned short* Wrow  = &W_lds[(n0l + fr) * WSF + q * 8];
    for (int kb = 0; kb < NKB; ++kb) {
        __syncthreads();
        {
            uint4v lo = { pack2(wv0.x, wv0.y), pack2(wv0.z, wv0.w),
                          pack2(wv1.x, wv1.y), pack2(wv1.z, wv1.w) };
            uint4v hi = { pack2(wv2.x, wv2.y), pack2(wv2.z, wv2.w),
                          pack2(wv3.x, wv3.y), pack2(wv3.z, wv3.w) };
            *(uint4v*)&W_lds[wn * WSF + wk]     = lo;
            *(uint4v*)&W_lds[wn * WSF + wk + 8] = hi;
        }
        if (kb < NKB - 1) {
            const float* Wn = Wbase + (size_t)(kb + 1) * 32;
            wv0 = *(const float4v*)(Wn + 0);
            wv1 = *(const float4v*)(Wn + 4);
            wv2 = *(const float4v*)(Wn + 8);
            wv3 = *(const float4v*)(Wn + 12);
        }
        __syncthreads();
        short8 a0 = *(const short8*)(Arow0 + kb * 32);
        short8 a1 = *(const short8*)(Arow1 + kb * 32);
        short8 b0 = *(const short8*)(Wrow + 0 * 16 * WSF);
        short8 b1 = *(const short8*)(Wrow + 1 * 16 * WSF);
        short8 b2 = *(const short8*)(Wrow + 2 * 16 * WSF);
        short8 b3 = *(const short8*)(Wrow + 3 * 16 * WSF);
        acc[0][0] = __builtin_amdgcn_mfma_f32_16x16x32_bf16(a0, b0, acc[0][0], 0, 0, 0);
        acc[0][1] = __builtin_amdgcn_mfma_f32_16x16x32_bf16(a0, b1, acc[0][1], 0, 0, 0);
        acc[0][2] = __builtin_amdgcn_mfma_f32_16x16x32_bf16(a0, b2, acc[0][2], 0, 0, 0);
        acc[0][3] = __builtin_amdgcn_mfma_f32_16x16x32_bf16(a0, b3, acc[0][3], 0, 0, 0);
        acc[1][0] = __builtin_amdgcn_mfma_f32_16x16x32_bf16(a1, b0, acc[1][0], 0, 0, 0);
        acc[1][1] = __builtin_amdgcn_mfma_f32_16x16x32_bf16(a1, b1, acc[1][1], 0, 0, 0);
        acc[1][2] = __builtin_amdgcn_mfma_f32_16x16x32_bf16(a1, b2, acc[1][2], 0, 0, 0);
        acc[1][3] = __builtin_amdgcn_mfma_f32_16x16x32_bf16(a1, b3, acc[1][3], 0, 0, 0);
    }
    const int colbase = ntile * 128 + n0l + fr;
    #pragma unroll
    for (int mt = 0; mt < 2; ++mt) {
        #pragma unroll
        for (int r = 0; r < 4; ++r) {
            const int hrow = m0 + mt * 16 + q * 4 + r;
            float* po = out + ((size_t)b * SS + (size_t)hrow * 128 + sc) * EE + colbase;
            po[0 * 16] = acc[mt][0][r];
            po[1 * 16] = acc[mt][1][r];
            po[2 * 16] = acc[mt][2][r];
            po[3 * 16] = acc[mt][3][r];
        }
    }
}

extern "C" void kernel_launch(void* const* d_in, const int* in_sizes, int n_in,
                              void* d_out, int out_size, void* d_ws, size_t ws_size,
                              hipStream_t stream) {
    const float* x     = (const float*)d_in[0];
    const float* theta = (const float*)d_in[1];
    const float* W     = (const float*)d_in[2];
    float* out         = (float*)d_out;

    if (ws_size >= (size_t)EE * EE * sizeof(unsigned short)) {
        unsigned short* Wws = (unsigned short*)d_ws;
        w_prep<<<dim3(256), dim3(256), 0, stream>>>(W, Wws);
        qmha_fused3<<<dim3(4096), dim3(256), 0, stream>>>(x, theta, Wws, out);
    } else {
        qmha_fused_fb<<<dim3(4096), dim3(256), 0, stream>>>(x, theta, W, out);
    }
}

// Round 2
// 246.655 us; speedup vs baseline: 1.1519x; 1.1123x over previous
//
#include <hip/hip_runtime.h>
#include <hip/hip_bf16.h>

typedef __attribute__((ext_vector_type(8))) short short8;
typedef __attribute__((ext_vector_type(4))) float float4v;
typedef __attribute__((ext_vector_type(4))) unsigned int uint4v;
typedef __attribute__((ext_vector_type(2))) unsigned int uint2v;

#define SS 8192
#define EE 512
#define NKB 16
#define APAD 40   // A-slice row pitch in shorts (80 B: conflict-free stride)

__device__ __forceinline__ unsigned int f2bf1(float f) {
    unsigned int u = __builtin_bit_cast(unsigned int, f);
    return (u + 0x7fffu + ((u >> 16) & 1u)) >> 16;   // RNE, inputs finite
}
__device__ __forceinline__ unsigned int pack2(float lo, float hi) {
    return f2bf1(lo) | (f2bf1(hi) << 16);
}
__device__ __forceinline__ void gl_lds16(const void* g, void* l) {
    __builtin_amdgcn_global_load_lds(
        (const __attribute__((address_space(1))) void*)g,
        (__attribute__((address_space(3))) void*)l, 16, 0, 0);
}

#define WAITV(n) asm volatile("s_waitcnt vmcnt(" #n ")" ::: "memory")
#define WAITL()  asm volatile("s_waitcnt lgkmcnt(0)" ::: "memory")
#define MEMBAR() asm volatile("" ::: "memory")

// ---------- prep: W fp32 [512][512] -> bf16 ws [kb][n][swizzled 32k] ----------
// In-LDS read addr will be n*32 + (q ^ ((n>>1)&3))*8; bake the same XOR here so
// the DMA stays a linear copy (swizzle on source + on read = both-sides rule).
__global__ void w_prep(const float* __restrict__ W, unsigned short* __restrict__ Wws) {
    int idx = blockIdx.x * 256 + threadIdx.x;        // 65536 threads x 4 elems
    int n  = idx >> 7;                               // row 0..511
    int kg = idx & 127;
    int k  = kg * 4;
    float4v v = *(const float4v*)(W + (size_t)n * EE + k);
    int kb = k >> 5, kl = k & 31;
    int slot = ((kl >> 3) ^ ((n >> 1) & 3));
    int j = kl & 7;                                  // 0 or 4
    unsigned short* dst = Wws + ((size_t)kb * (EE * 32) + (size_t)n * 32 + slot * 8 + j);
    uint2v pk = { pack2(v.x, v.y), pack2(v.z, v.w) };
    *(uint2v*)dst = pk;
}

// ---------- main v4: N=512/block, streamed A+W slices, wave-local W DMA ----------
// Block = (b, sc): full 64x512 output panel. K streamed in 16 slices of 32.
// W: wave wid DMAs rows [wid*128, +128) of each slice -> only its own vmcnt
//    gates readiness (no barrier for W). Double-buffered, counted vmcnt waits.
// A: 4 KB slice/kb (rows from cos(x)), double-buffered, 1 barrier per kb.
__global__ __launch_bounds__(256, 2)
void qmha_fused4(const float* __restrict__ x, const float* __restrict__ theta,
                 const unsigned short* __restrict__ Wws, float* __restrict__ out)
{
    __shared__ __attribute__((aligned(16))) unsigned short W_lds[2][EE * 32];   // 65536 B
    __shared__ __attribute__((aligned(16))) unsigned short A_lds[2][64 * APAD]; // 10240 B

    const int bx = blockIdx.x;                       // 1024 blocks
    const int b  = bx >> 7;
    const int sc = bx & 127;
    const int t = threadIdx.x, lane = t & 63, wid = t >> 6;
    const int fr = lane & 15, q = lane >> 4;

    // W DMA: wave wid owns shorts [wid*4096, +4096) of each 16384-short slice
    const unsigned short* wsrc_base = Wws + (size_t)wid * 4096 + lane * 8;
    const int wdst_off = wid * 4096 + lane * 8;

    // x staging: wave wid loads x row (sc*64 + kb*4 + wid), lane covers e=lane*8..+8
    const float* xrow_base = x + ((size_t)b * SS + (size_t)sc * 64 + wid) * EE + lane * 8;

    // A-slice write: [m=lane][k=wid*8..+8], pitch APAD
    const int aw_off = lane * APAD + wid * 8;

    // frag read offsets: a: row fr+16mt, k-chunk q*8 ; b: row wid*128+fr+16nt, swizzled slot
    const int aoff = fr * APAD + q * 8;
    const int boff = (wid * 128 + fr) * 32 + ((q ^ ((fr >> 1) & 3)) * 8);

    const float th0 = theta[0], th1 = theta[1], th2 = theta[2], th3 = theta[3];
    const float th4 = theta[4], th5 = theta[5], th6 = theta[6], th7 = theta[7];

    float4v acc[4][8];
    #pragma unroll
    for (int i = 0; i < 4; ++i)
        #pragma unroll
        for (int j2 = 0; j2 < 8; ++j2)
            acc[i][j2] = (float4v){0.f, 0.f, 0.f, 0.f};

#define ISSUE_W(kbv) do { \
    const unsigned short* _s = wsrc_base + (size_t)(kbv) * (EE * 32); \
    unsigned short* _d = (unsigned short*)W_lds[(kbv) & 1] + wdst_off; \
    gl_lds16(_s + 0 * 512, _d + 0 * 512); \
    gl_lds16(_s + 1 * 512, _d + 1 * 512); \
    gl_lds16(_s + 2 * 512, _d + 2 * 512); \
    gl_lds16(_s + 3 * 512, _d + 3 * 512); \
    gl_lds16(_s + 4 * 512, _d + 4 * 512); \
    gl_lds16(_s + 5 * 512, _d + 5 * 512); \
    gl_lds16(_s + 6 * 512, _d + 6 * 512); \
    gl_lds16(_s + 7 * 512, _d + 7 * 512); \
} while (0)

#define COS_WRITE(kbv, va, vb) do { \
    float _c0 = __cosf((va).x + th0), _c1 = __cosf((va).y + th1); \
    float _c2 = __cosf((va).z + th2), _c3 = __cosf((va).w + th3); \
    float _c4 = __cosf((vb).x + th4), _c5 = __cosf((vb).y + th5); \
    float _c6 = __cosf((vb).z + th6), _c7 = __cosf((vb).w + th7); \
    uint4v _pk = { pack2(_c0,_c1), pack2(_c2,_c3), pack2(_c4,_c5), pack2(_c6,_c7) }; \
    *(uint4v*)&A_lds[(kbv) & 1][aw_off] = _pk; \
} while (0)

    // ---- prologue: slices 0,1 in flight; stage A0; barrier ----
    float4v xA0, xA1, xB0, xB1;
    { const float* _p = xrow_base;              xA0 = *(const float4v*)_p; xA1 = *(const float4v*)(_p + 4); }
    MEMBAR();
    ISSUE_W(0);
    MEMBAR();
    { const float* _p = xrow_base + 4 * EE;     xB0 = *(const float4v*)_p; xB1 = *(const float4v*)(_p + 4); }
    MEMBAR();
    ISSUE_W(1);
    MEMBAR();
    WAITV(18);                 // x0 arrived (W0:8 + x1:2 + W1:8 = 18 in flight)
    COS_WRITE(0, xA0, xA1);
    WAITV(10);                 // W0 done (own quarter); x1+W1 stay in flight
    WAITL();
    __builtin_amdgcn_s_barrier();

    // ---- steady bodies kb = 0..13 ----
    // ledger entering body kb: x_{kb+1}(2), W_{kb+1}(8) outstanding
#define BODY_FULL(kbv, xCa, xCb, xNa, xNb) do { \
    { const float* _p = xrow_base + (size_t)((kbv) + 2) * (4 * EE); \
      xNa = *(const float4v*)_p; xNb = *(const float4v*)(_p + 4); }            /* +2 -> 12 */ \
    MEMBAR(); \
    const unsigned short* _Ab = A_lds[(kbv) & 1]; \
    const unsigned short* _Bb = W_lds[(kbv) & 1]; \
    short8 _af[4], _bf[8]; \
    _Pragma("unroll") for (int _mt = 0; _mt < 4; ++_mt) \
        _af[_mt] = *(const short8*)&_Ab[aoff + _mt * 16 * APAD]; \
    _Pragma("unroll") for (int _nt = 0; _nt < 8; ++_nt) \
        _bf[_nt] = *(const short8*)&_Bb[boff + _nt * 512]; \
    WAITL();                    /* frag reads complete BEFORE next DMA can touch this buf */ \
    ISSUE_W((kbv) + 2);                                                         /* +8 -> 20 */ \
    MEMBAR(); \
    __builtin_amdgcn_s_setprio(1); \
    _Pragma("unroll") for (int _nt = 0; _nt < 8; ++_nt) \
        _Pragma("unroll") for (int _mt = 0; _mt < 4; ++_mt) \
            acc[_mt][_nt] = __builtin_amdgcn_mfma_f32_16x16x32_bf16(_af[_mt], _bf[_nt], acc[_mt][_nt], 0, 0, 0); \
    __builtin_amdgcn_s_setprio(0); \
    WAITV(18);                  /* x_{kb+1} arrived */ \
    COS_WRITE((kbv) + 1, xCa, xCb); \
    WAITV(10);                  /* W_{kb+1} landed; x_{kb+2}+W_{kb+2} stay in flight */ \
    WAITL(); \
    __builtin_amdgcn_s_barrier(); \
} while (0)

    for (int kb = 0; kb < 14; kb += 2) {
        BODY_FULL(kb,     xB0, xB1, xA0, xA1);
        BODY_FULL(kb + 1, xA0, xA1, xB0, xB1);
    }

    // ---- body 14: no more issues; drain tail ----
    {
        const unsigned short* _Ab = A_lds[0];
        const unsigned short* _Bb = W_lds[0];
        short8 _af[4], _bf[8];
        #pragma unroll
        for (int _mt = 0; _mt < 4; ++_mt) _af[_mt] = *(const short8*)&_Ab[aoff + _mt * 16 * APAD];
        #pragma unroll
        for (int _nt = 0; _nt < 8; ++_nt) _bf[_nt] = *(const short8*)&_Bb[boff + _nt * 512];
        __builtin_amdgcn_s_setprio(1);
        #pragma unroll
        for (int _nt = 0; _nt < 8; ++_nt)
            #pragma unroll
            for (int _mt = 0; _mt < 4; ++_mt)
                acc[_mt][_nt] = __builtin_amdgcn_mfma_f32_16x16x32_bf16(_af[_mt], _bf[_nt], acc[_mt][_nt], 0, 0, 0);
        __builtin_amdgcn_s_setprio(0);
        WAITV(8);               // x15 arrived (W15:8 remain)
        COS_WRITE(15, xB0, xB1);
        WAITV(0);               // W15 landed (tail only)
        WAITL();
        __builtin_amdgcn_s_barrier();
    }
    // ---- body 15: compute only ----
    {
        const unsigned short* _Ab = A_lds[1];
        const unsigned short* _Bb = W_lds[1];
        short8 _af[4], _bf[8];
        #pragma unroll
        for (int _mt = 0; _mt < 4; ++_mt) _af[_mt] = *(const short8*)&_Ab[aoff + _mt * 16 * APAD];
        #pragma unroll
        for (int _nt = 0; _nt < 8; ++_nt) _bf[_nt] = *(const short8*)&_Bb[boff + _nt * 512];
        #pragma unroll
        for (int _nt = 0; _nt < 8; ++_nt)
            #pragma unroll
            for (int _mt = 0; _mt < 4; ++_mt)
                acc[_mt][_nt] = __builtin_amdgcn_mfma_f32_16x16x32_bf16(_af[_mt], _bf[_nt], acc[_mt][_nt], 0, 0, 0);
    }

    // ---- epilogue: C/D col=lane&15, row=(lane>>4)*4+reg (validated mapping) ----
    // out(m = mt*16 + q*4 + r, n = wid*128 + nt*16 + fr) at [b, m*128+sc, n]
    float* outb = out + (size_t)b * (SS * EE) + (size_t)sc * EE + wid * 128 + fr;
    #pragma unroll
    for (int mt = 0; mt < 4; ++mt) {
        #pragma unroll
        for (int r = 0; r < 4; ++r) {
            const int m = mt * 16 + q * 4 + r;
            float* po = outb + (size_t)m * (128 * EE);
            #pragma unroll
            for (int nt = 0; nt < 8; ++nt)
                po[nt * 16] = acc[mt][nt][r];
        }
    }
#undef BODY_FULL
#undef ISSUE_W
#undef COS_WRITE
}

// ---------- fallback (round-1 kernel, used only if ws too small) ----------
#define AS 520
#define WSF 40
#define HH 64
__global__ __launch_bounds__(256, 2)
void qmha_fused_fb(const float* __restrict__ x, const float* __restrict__ theta,
                   const float* __restrict__ W, float* __restrict__ out)
{
    __shared__ __attribute__((aligned(16))) unsigned short A_lds[HH * AS];
    __shared__ __attribute__((aligned(16))) unsigned short W_lds[128 * WSF];
    const int bx = blockIdx.x;
    const int ntile = (bx >> 3) & 3;
    const int p = ((bx >> 5) << 3) | (bx & 7);
    const int b = p >> 7;
    const int sc = p & 127;
    const int t = threadIdx.x, lane = t & 63, wid = t >> 6;
    const int wn = t >> 1, wk = (t & 1) * 16;
    const float* Wbase = W + (size_t)(ntile * 128 + wn) * EE + wk;
    float4v wv0 = *(const float4v*)(Wbase + 0);
    float4v wv1 = *(const float4v*)(Wbase + 4);
    float4v wv2 = *(const float4v*)(Wbase + 8);
    float4v wv3 = *(const float4v*)(Wbase + 12);
    const float th0 = theta[0], th1 = theta[1], th2 = theta[2], th3 = theta[3];
    const float th4 = theta[4], th5 = theta[5], th6 = theta[6], th7 = theta[7];
    {
        const float* xb = x + ((size_t)b * SS + (size_t)sc * 64) * EE + lane * 8;
        #pragma unroll
        for (int it = 0; it < 16; ++it) {
            const int s_loc = wid * 16 + it;
            const float* px = xb + (size_t)s_loc * EE;
            float4v v0 = *(const float4v*)(px);
            float4v v1 = *(const float4v*)(px + 4);
            float c0 = __cosf(v0.x + th0), c1 = __cosf(v0.y + th1);
            float c2 = __cosf(v0.z + th2), c3 = __cosf(v0.w + th3);
            float c4 = __cosf(v1.x + th4), c5 = __cosf(v1.y + th5);
            float c6 = __cosf(v1.z + th6), c7 = __cosf(v1.w + th7);
            uint4v pk = { pack2(c0,c1), pack2(c2,c3), pack2(c4,c5), pack2(c6,c7) };
            *(uint4v*)&A_lds[lane * AS + s_loc * 8] = pk;
        }
    }
    float4v acc[2][4];
    #pragma unroll
    for (int i = 0; i < 2; ++i)
        #pragma unroll
        for (int j = 0; j < 4; ++j)
            acc[i][j] = (float4v){0.f, 0.f, 0.f, 0.f};
    const int m0 = (wid >> 1) * 32, n0l = (wid & 1) * 64;
    const int fr = lane & 15, q = lane >> 4;
    const unsigned short* Arow0 = &A_lds[(m0 + fr) * AS + q * 8];
    const unsigned short* Arow1 = Arow0 + 16 * AS;
    const unsigned short* Wrow  = &W_lds[(n0l + fr) * WSF + q * 8];
    for (int kb = 0; kb < NKB; ++kb) {
        __syncthreads();
        {
            uint4v lo = { pack2(wv0.x, wv0.y), pack2(wv0.z, wv0.w),
                          pack2(wv1.x, wv1.y), pack2(wv1.z, wv1.w) };
            uint4v hi = { pack2(wv2.x, wv2.y), pack2(wv2.z, wv2.w),
                          pack2(wv3.x, wv3.y), pack2(wv3.z, wv3.w) };
            *(uint4v*)&W_lds[wn * WSF + wk]     = lo;
            *(uint4v*)&W_lds[wn * WSF + wk + 8] = hi;
        }
        if (kb < NKB - 1) {
            const float* Wn = Wbase + (size_t)(kb + 1) * 32;
            wv0 = *(const float4v*)(Wn + 0);
            wv1 = *(const float4v*)(Wn + 4);
            wv2 = *(const float4v*)(Wn + 8);
            wv3 = *(const float4v*)(Wn + 12);
        }
        __syncthreads();
        short8 a0 = *(const short8*)(Arow0 + kb * 32);
        short8 a1 = *(const short8*)(Arow1 + kb * 32);
        short8 b0 = *(const short8*)(Wrow + 0 * 16 * WSF);
        short8 b1 = *(const short8*)(Wrow + 1 * 16 * WSF);
        short8 b2 = *(const short8*)(Wrow + 2 * 16 * WSF);
        short8 b3 = *(const short8*)(Wrow + 3 * 16 * WSF);
        acc[0][0] = __builtin_amdgcn_mfma_f32_16x16x32_bf16(a0, b0, acc[0][0], 0, 0, 0);
        acc[0][1] = __builtin_amdgcn_mfma_f32_16x16x32_bf16(a0, b1, acc[0][1], 0, 0, 0);
        acc[0][2] = __builtin_amdgcn_mfma_f32_16x16x32_bf16(a0, b2, acc[0][2], 0, 0, 0);
        acc[0][3] = __builtin_amdgcn_mfma_f32_16x16x32_bf16(a0, b3, acc[0][3], 0, 0, 0);
        acc[1][0] = __builtin_amdgcn_mfma_f32_16x16x32_bf16(a1, b0, acc[1][0], 0, 0, 0);
        acc[1][1] = __builtin_amdgcn_mfma_f32_16x16x32_bf16(a1, b1, acc[1][1], 0, 0, 0);
        acc[1][2] = __builtin_amdgcn_mfma_f32_16x16x32_bf16(a1, b2, acc[1][2], 0, 0, 0);
        acc[1][3] = __builtin_amdgcn_mfma_f32_16x16x32_bf16(a1, b3, acc[1][3], 0, 0, 0);
    }
    const int colbase = ntile * 128 + n0l + fr;
    #pragma unroll
    for (int mt = 0; mt < 2; ++mt) {
        #pragma unroll
        for (int r = 0; r < 4; ++r) {
            const int hrow = m0 + mt * 16 + q * 4 + r;
            float* po = out + ((size_t)b * SS + (size_t)hrow * 128 + sc) * EE + colbase;
            po[0 * 16] = acc[mt][0][r];
            po[1 * 16] = acc[mt][1][r];
            po[2 * 16] = acc[mt][2][r];
            po[3 * 16] = acc[mt][3][r];
        }
    }
}

extern "C" void kernel_launch(void* const* d_in, const int* in_sizes, int n_in,
                              void* d_out, int out_size, void* d_ws, size_t ws_size,
                              hipStream_t stream) {
    const float* x     = (const float*)d_in[0];
    const float* theta = (const float*)d_in[1];
    const float* W     = (const float*)d_in[2];
    float* out         = (float*)d_out;

    if (ws_size >= (size_t)EE * EE * sizeof(unsigned short)) {
        unsigned short* Wws = (unsigned short*)d_ws;
        w_prep<<<dim3(256), dim3(256), 0, stream>>>(W, Wws);
        qmha_fused4<<<dim3(1024), dim3(256), 0, stream>>>(x, theta, Wws, out);
    } else {
        qmha_fused_fb<<<dim3(4096), dim3(256), 0, stream>>>(x, theta, W, out);
    }
}